// Round 20
// baseline (97.514 us; speedup 1.0000x reference)
//
#include <hip/hip_runtime.h>
#include <hip/hip_bf16.h>

#define EMBED 1024
#define HEAD 64
#define SEQ 4096

typedef __attribute__((ext_vector_type(8))) short short8;
typedef __attribute__((ext_vector_type(4))) float f32x4;

union S8u { short8 v; uint u[4]; ushort s[8]; };
union U4f { uint4 q; float f[4]; };

// manual RNE f32->bf16 (flash PV path — proven numerics)
__device__ __forceinline__ ushort f2bf(float f) {
  union { float f; uint u; } x; x.f = f;
  return (ushort)((x.u + 0x7fffu + ((x.u >> 16) & 1u)) >> 16);
}

// native cast (proj/prep bulk conversion)
__device__ __forceinline__ ushort f2bf_n(float f) {
  union { __hip_bfloat16 h; ushort u; } cv;
  cv.h = __float2bfloat16(f);
  return cv.u;
}

__device__ __forceinline__ short8 ld16(const ushort* p) {
  uint4 q = *(const uint4*)p;
  S8u t; t.u[0] = q.x; t.u[1] = q.y; t.u[2] = q.z; t.u[3] = q.w;
  return t.v;
}

// ---------------- kernel 1: transpose weights to bf16 wT[t][c][k] ----------------
__global__ __launch_bounds__(256) void prep_w(const float* __restrict__ wq,
                                              const float* __restrict__ wk,
                                              const float* __restrict__ wv,
                                              ushort* __restrict__ wT) {
  int idx = blockIdx.x * 256 + threadIdx.x;
  if (idx >= 3 * HEAD * EMBED) return;
  int t = idx >> 16;
  int rem = idx & 0xFFFF;
  int c = rem >> 10;
  int k = rem & 1023;
  const float* w = (t == 0) ? wq : (t == 1) ? wk : wv;
  wT[idx] = f2bf_n(w[k * HEAD + c]);
}

// ------ kernel 2: projections — r17-proven inner pipeline, SPLIT-K=2 across blocks.
//  grid (256,3,2): kz owns k-chunks [kz*8, kz*8+8). Inner loop byte-identical to r17.
//  Epilogue: linear f32 partial write (simpler than r17's; formats applied in combine).
__global__ __launch_bounds__(256, 3) void proj_kernel(
    const float* __restrict__ qsrc, const float* __restrict__ ksrc,
    const float* __restrict__ vsrc, const ushort* __restrict__ wT,
    float* __restrict__ Ppart) {
  // A f32 [64][64] swizzled @0 (16 KB), B bf16 [64][64] swizzled @16384 (8 KB)
  __shared__ __align__(16) char smem[24576];

  const int t = blockIdx.y;
  const int kz = blockIdx.z;
  const float* src = (t == 0) ? qsrc : (t == 1) ? ksrc : vsrc;
  const ushort* wt = wT + t * (HEAD * EMBED);
  const int tid = threadIdx.x;
  const int lane = tid & 63;
  const int wid = tid >> 6;
  const int c = lane & 15;
  const int g = lane >> 4;
  const int row0 = blockIdx.x * 64;
  const int phase = (blockIdx.x + 5 * blockIdx.y) & 7;   // decorrelate k-chunks (sum reorder)

  // ---- staging addresses (coalesced global, swizzled LDS dest) — r11/r17-proven ----
  const float* gA = src + (size_t)(row0 + (tid >> 4)) * EMBED + (tid & 15) * 4;
  const ushort* gB = wt + (size_t)(tid >> 3) * EMBED + (tid & 7) * 8;
  const int wA = (tid >> 4) * 256 + (((tid & 15) * 16) ^ (((tid >> 4) & 7) << 4));
  const int wB = 16384 + (tid >> 3) * 128 + (((tid & 7) * 16) ^ (((tid >> 3) & 7) << 4));

  // ---- fragment-read offsets ----
  const int rA = (wid * 16 + c) * 256;
  const int swc = (c & 7) << 4;

  f32x4 acc[4];
#pragma unroll
  for (int i = 0; i < 4; ++i) acc[i] = {0.f, 0.f, 0.f, 0.f};

  // prologue: loads for this kz-half's chunk 'phase'
  uint4 sA0, sA1, sA2, sA3, sB0, sB1;
  {
    const int ki = (kz * 8 + phase) * 64;
    sA0 = *(const uint4*)(gA + ki);
    sA1 = *(const uint4*)(gA + 16384 + ki);
    sA2 = *(const uint4*)(gA + 32768 + ki);
    sA3 = *(const uint4*)(gA + 49152 + ki);
    sB0 = *(const uint4*)(gB + ki);
    sB1 = *(const uint4*)(gB + 32768 + ki);
  }

  for (int r = 0; r < 8; ++r) {
    // ---- write staged regs to LDS (swizzled dest) ----
    *(uint4*)(smem + wA)         = sA0;
    *(uint4*)(smem + wA + 4096)  = sA1;
    *(uint4*)(smem + wA + 8192)  = sA2;
    *(uint4*)(smem + wA + 12288) = sA3;
    *(uint4*)(smem + wB)         = sB0;
    *(uint4*)(smem + wB + 4096)  = sB1;
    __syncthreads();

    // ---- issue next k-chunk's loads (in flight during compute) ----
    if (r + 1 < 8) {
      const int ki = (kz * 8 + ((r + 1 + phase) & 7)) * 64;
      sA0 = *(const uint4*)(gA + ki);
      sA1 = *(const uint4*)(gA + 16384 + ki);
      sA2 = *(const uint4*)(gA + 32768 + ki);
      sA3 = *(const uint4*)(gA + 49152 + ki);
      sB0 = *(const uint4*)(gB + ki);
      sB1 = *(const uint4*)(gB + 32768 + ki);
    }

    // ---- compute: 2 k-steps x 4 nf MFMAs from LDS (identical to r17) ----
#pragma unroll
    for (int s = 0; s < 2; ++s) {
      U4f af0, af1;
      af0.q = *(const uint4*)(smem + rA + ((128 * s + 32 * g) ^ swc));
      af1.q = *(const uint4*)(smem + rA + ((128 * s + 32 * g + 16) ^ swc));
      S8u a;
      a.s[0] = f2bf_n(af0.f[0]); a.s[1] = f2bf_n(af0.f[1]);
      a.s[2] = f2bf_n(af0.f[2]); a.s[3] = f2bf_n(af0.f[3]);
      a.s[4] = f2bf_n(af1.f[0]); a.s[5] = f2bf_n(af1.f[1]);
      a.s[6] = f2bf_n(af1.f[2]); a.s[7] = f2bf_n(af1.f[3]);
#pragma unroll
      for (int nf = 0; nf < 4; ++nf) {
        uint4 bq = *(const uint4*)(smem + 16384 + (16 * nf + c) * 128 + ((64 * s + 16 * g) ^ swc));
        S8u b; b.u[0] = bq.x; b.u[1] = bq.y; b.u[2] = bq.z; b.u[3] = bq.w;
        acc[nf] = __builtin_amdgcn_mfma_f32_16x16x32_bf16(a.v, b.v, acc[nf], 0, 0, 0);
      }
    }
    __syncthreads();
  }

  // ---- epilogue: linear f32 partial (C/D layout col=lane&15, row=4*(lane>>4)+reg) ----
  float* pp = Ppart + ((size_t)(t * 2 + kz) * 16384 + row0) * 64;
  const int rb = wid * 16 + 4 * g;
#pragma unroll
  for (int nf = 0; nf < 4; ++nf)
#pragma unroll
    for (int rr = 0; rr < 4; ++rr)
      pp[(rb + rr) * 64 + nf * 16 + c] = acc[nf][rr];
}

// ---- kernel 2b: combine the 2 split-K partials; apply output formats ----
__global__ __launch_bounds__(256) void combine_kernel(
    const float* __restrict__ Ppart, ushort* __restrict__ qb,
    ushort* __restrict__ kb, ushort* __restrict__ vt) {
  __shared__ ushort vtile[64][72];
  const int t = blockIdx.y;
  const int row0 = blockIdx.x * 64;
  const int tid = threadIdx.x;
  const float* p0 = Ppart + ((size_t)(t * 2 + 0) * 16384 + row0) * 64;
  const float* p1 = Ppart + ((size_t)(t * 2 + 1) * 16384 + row0) * 64;

  if (t < 2) {
    const float scale = (t == 0) ? 0.18033688011112042f : 1.0f;  // 0.125*log2(e)
    ushort* dst = ((t == 0) ? qb : kb) + (size_t)row0 * 64;
#pragma unroll
    for (int j = 0; j < 4; ++j) {
      int f4 = tid + j * 256;                 // 0..1023 float4s of this 64x64 tile
      f32x4 a = *(const f32x4*)(p0 + f4 * 4);
      f32x4 b = *(const f32x4*)(p1 + f4 * 4);
      ushort o[4];
#pragma unroll
      for (int e = 0; e < 4; ++e) o[e] = f2bf_n((a[e] + b[e]) * scale);
      *(uint2*)(dst + f4 * 4) = *(const uint2*)o;   // 8B coalesced store
    }
  } else {
    // V: sum partials, transpose via LDS (proven vtile pattern), coalesced row writes
    const int r = tid >> 2;                   // 0..63: s-row within band
    const int cc = (tid & 3) * 16;            // d-col base
#pragma unroll
    for (int j = 0; j < 4; ++j) {
      f32x4 a = *(const f32x4*)(p0 + r * 64 + cc + j * 4);
      f32x4 b = *(const f32x4*)(p1 + r * 64 + cc + j * 4);
#pragma unroll
      for (int e = 0; e < 4; ++e)
        vtile[cc + j * 4 + e][r] = f2bf_n(a[e] + b[e]);
    }
    __syncthreads();
    int d = tid >> 2;
    int s0 = (tid & 3) << 4;
    int bb = row0 >> 12;
    int sbase = row0 & (SEQ - 1);
    ushort* dstv = vt + ((size_t)(bb * HEAD + d) << 12) + sbase + s0;
    const uint4* srcp = (const uint4*)&vtile[d][s0];
    *(uint4*)dstv = srcp[0];
    *(uint4*)(dstv + 8) = srcp[1];
  }
}

// -- kernel 3: flash attn — 256-q block, 8 waves SHARE each staged KV tile (reuse x8),
//    4-way kv-chunk across blocks, partials to workspace. (round-9-proven, untouched)
__global__ __launch_bounds__(512, 2) void flash_kernel(
    const ushort* __restrict__ qb, const ushort* __restrict__ kb,
    const ushort* __restrict__ vt, float* __restrict__ Opart,
    float* __restrict__ mlpart) {
  __shared__ __align__(16) char smem[16384];   // K tile @0 (8KB), V tile @8192 (8KB)

  const int tid = threadIdx.x;
  const int lane = tid & 63;
  const int w = tid >> 6;
  const int c = lane & 15, g = lane >> 4;

  const int bid = blockIdx.x;
  const int band = 15 - (bid >> 4);
  const int b = (bid >> 2) & 3;
  const int j = bid & 3;
  const int ck = band + 1;
  const int kt0 = j * ck;
  const int q0w = band * 256 + w * 32;

  const int srow = tid >> 3;
  const int scol = (tid & 7) << 4;
  const int sdst = srow * 128 + (scol ^ ((srow & 7) << 4));
  const char* kgp = (const char*)(kb + (size_t)b * SEQ * HEAD) + (size_t)kt0 * 8192 + tid * 16;
  const char* vgp = (const char*)(vt + (size_t)b * HEAD * SEQ) + (size_t)srow * 8192 + kt0 * 128 + scol;

  short8 qa[2][2];
#pragma unroll
  for (int qf = 0; qf < 2; ++qf) {
    const ushort* qrow = qb + (size_t)(b * SEQ + q0w + 16 * qf + c) * HEAD + 8 * g;
    qa[qf][0] = ld16(qrow);
    qa[qf][1] = ld16(qrow + 32);
  }

  f32x4 O[4][2];
#pragma unroll
  for (int i = 0; i < 4; ++i)
#pragma unroll
    for (int qf = 0; qf < 2; ++qf) O[i][qf] = {0.f, 0.f, 0.f, 0.f};
  float m[2] = {-1e30f, -1e30f};
  float l[2] = {0.f, 0.f};

  uint4 sK = *(const uint4*)kgp;
  uint4 sV = *(const uint4*)vgp;

  for (int r = 0; r < ck; ++r) {
    *(uint4*)(smem + sdst) = sK;
    *(uint4*)(smem + 8192 + sdst) = sV;
    __syncthreads();

    if (r + 1 < ck) {
      kgp += 8192; vgp += 128;
      sK = *(const uint4*)kgp;
      sV = *(const uint4*)vgp;
    }

    const int kt = kt0 + r;
    const int k0 = kt << 6;
    if (k0 <= q0w + 31) {
      f32x4 Sf[4][2];
#pragma unroll
      for (int i = 0; i < 4; ++i)
#pragma unroll
        for (int qf = 0; qf < 2; ++qf) Sf[i][qf] = {0.f, 0.f, 0.f, 0.f};
#pragma unroll
      for (int nf = 0; nf < 4; ++nf) {
        int row = 16 * nf + c;
        int sw = (row & 7) << 4;
        uint4 kv = *(const uint4*)(smem + row * 128 + ((16 * g) ^ sw));
        S8u ka0;
        ka0.u[0] = kv.x; ka0.u[1] = kv.y; ka0.u[2] = kv.z; ka0.u[3] = kv.w;
#pragma unroll
        for (int qf = 0; qf < 2; ++qf)
          Sf[nf][qf] = __builtin_amdgcn_mfma_f32_16x16x32_bf16(ka0.v, qa[qf][0], Sf[nf][qf], 0, 0, 0);
        uint4 kv2 = *(const uint4*)(smem + row * 128 + ((64 + 16 * g) ^ sw));
        S8u ka1;
        ka1.u[0] = kv2.x; ka1.u[1] = kv2.y; ka1.u[2] = kv2.z; ka1.u[3] = kv2.w;
#pragma unroll
        for (int qf = 0; qf < 2; ++qf)
          Sf[nf][qf] = __builtin_amdgcn_mfma_f32_16x16x32_bf16(ka1.v, qa[qf][1], Sf[nf][qf], 0, 0, 0);
      }

      if (k0 + 63 > q0w) {
#pragma unroll
        for (int nf = 0; nf < 4; ++nf)
#pragma unroll
          for (int qf = 0; qf < 2; ++qf)
#pragma unroll
            for (int rr = 0; rr < 4; ++rr)
              if (k0 + nf * 16 + 4 * g + rr > q0w + 16 * qf + c) Sf[nf][qf][rr] = -1e30f;
      }

#pragma unroll
      for (int qf = 0; qf < 2; ++qf) {
        float x0 = fmaxf(fmaxf(Sf[0][qf][0], Sf[0][qf][1]), fmaxf(Sf[0][qf][2], Sf[0][qf][3]));
        float x1 = fmaxf(fmaxf(Sf[1][qf][0], Sf[1][qf][1]), fmaxf(Sf[1][qf][2], Sf[1][qf][3]));
        float x2 = fmaxf(fmaxf(Sf[2][qf][0], Sf[2][qf][1]), fmaxf(Sf[2][qf][2], Sf[2][qf][3]));
        float x3 = fmaxf(fmaxf(Sf[3][qf][0], Sf[3][qf][1]), fmaxf(Sf[3][qf][2], Sf[3][qf][3]));
        float rm = fmaxf(fmaxf(x0, x1), fmaxf(x2, x3));
        rm = fmaxf(rm, __shfl_xor(rm, 16));
        rm = fmaxf(rm, __shfl_xor(rm, 32));
        rm = fmaxf(rm, m[qf]);
        float alpha = exp2f(m[qf] - rm);
        m[qf] = rm;
#pragma unroll
        for (int nf = 0; nf < 4; ++nf)
#pragma unroll
          for (int rr = 0; rr < 4; ++rr)
            Sf[nf][qf][rr] = exp2f(Sf[nf][qf][rr] - rm);
        float s0 = (Sf[0][qf][0] + Sf[0][qf][1]) + (Sf[0][qf][2] + Sf[0][qf][3]);
        float s1 = (Sf[1][qf][0] + Sf[1][qf][1]) + (Sf[1][qf][2] + Sf[1][qf][3]);
        float s2 = (Sf[2][qf][0] + Sf[2][qf][1]) + (Sf[2][qf][2] + Sf[2][qf][3]);
        float s3 = (Sf[3][qf][0] + Sf[3][qf][1]) + (Sf[3][qf][2] + Sf[3][qf][3]);
        float rs = (s0 + s1) + (s2 + s3);
        rs += __shfl_xor(rs, 16);
        rs += __shfl_xor(rs, 32);
        l[qf] = l[qf] * alpha + rs;
#pragma unroll
        for (int nf = 0; nf < 4; ++nf)
#pragma unroll
          for (int rr = 0; rr < 4; ++rr)
            O[nf][qf][rr] *= alpha;

#pragma unroll
        for (int sl = 0; sl < 2; ++sl) {
          S8u pa;
#pragma unroll
          for (int rr = 0; rr < 4; ++rr) {
            pa.s[rr]     = f2bf(Sf[2 * sl][qf][rr]);
            pa.s[rr + 4] = f2bf(Sf[2 * sl + 1][qf][rr]);
          }
#pragma unroll
          for (int nf = 0; nf < 4; ++nf) {
            int row = 16 * nf + c;
            int sw = (row & 7) << 4;
            S8u vbf;
            uint2 lo = *(const uint2*)(smem + 8192 + row * 128 + ((64 * sl + 8 * g) ^ sw));
            uint2 hi = *(const uint2*)(smem + 8192 + row * 128 + ((64 * sl + 32 + 8 * g) ^ sw));
            vbf.u[0] = lo.x; vbf.u[1] = lo.y; vbf.u[2] = hi.x; vbf.u[3] = hi.y;
            O[nf][qf] = __builtin_amdgcn_mfma_f32_16x16x32_bf16(vbf.v, pa.v, O[nf][qf], 0, 0, 0);
          }
        }
      }
    }
    __syncthreads();
  }

  const size_t pi = (size_t)((b * 16 + band) * 4 + j);
#pragma unroll
  for (int qf = 0; qf < 2; ++qf) {
    int ql = w * 32 + 16 * qf + c;
#pragma unroll
    for (int nf = 0; nf < 4; ++nf)
      *(f32x4*)&Opart[pi * 16384 + (size_t)ql * 64 + 16 * nf + 4 * g] = O[nf][qf];
    if (g == 0) {
      mlpart[pi * 512 + ql * 2]     = m[qf];
      mlpart[pi * 512 + ql * 2 + 1] = l[qf];
    }
  }
}

// ---------------- kernel 4: merge the 4 kv-chunk partials per band ----------------
__global__ __launch_bounds__(256) void merge_kernel(const float* __restrict__ Opart,
                                                    const float* __restrict__ mlpart,
                                                    float* __restrict__ out) {
  int i = blockIdx.x * 256 + threadIdx.x;
  int dq = i & 15;
  int row = i >> 4;
  int b = row >> 12;
  int qrow = row & 4095;
  int band = qrow >> 8;
  int q = qrow & 255;
  size_t pi0 = (size_t)((b * 16 + band) * 4);

  float mm[4], M = -1e30f;
#pragma unroll
  for (int jj = 0; jj < 4; ++jj) { mm[jj] = mlpart[(pi0 + jj) * 512 + q * 2]; M = fmaxf(M, mm[jj]); }
  float wgt[4], L = 0.f;
#pragma unroll
  for (int jj = 0; jj < 4; ++jj) {
    wgt[jj] = exp2f(mm[jj] - M);
    L += wgt[jj] * mlpart[(pi0 + jj) * 512 + q * 2 + 1];
  }
  f32x4 acc = {0.f, 0.f, 0.f, 0.f};
#pragma unroll
  for (int jj = 0; jj < 4; ++jj) {
    f32x4 t = *(const f32x4*)&Opart[(pi0 + jj) * 16384 + (size_t)q * 64 + 4 * dq];
#pragma unroll
    for (int rr = 0; rr < 4; ++rr) acc[rr] += wgt[jj] * t[rr];
  }
  float inv = 1.0f / L;
  f32x4 res;
#pragma unroll
  for (int rr = 0; rr < 4; ++rr) res[rr] = acc[rr] * inv;
  *(f32x4*)&out[(size_t)row * HEAD + 4 * dq] = res;
}

extern "C" void kernel_launch(void* const* d_in, const int* in_sizes, int n_in,
                              void* d_out, int out_size, void* d_ws, size_t ws_size,
                              hipStream_t stream) {
  const float* qsrc = (const float*)d_in[0];
  const float* ksrc = (const float*)d_in[1];
  const float* vsrc = (const float*)d_in[2];
  const float* wq = (const float*)d_in[3];
  const float* wk = (const float*)d_in[4];
  const float* wv = (const float*)d_in[5];
  float* out = (float*)d_out;

  char* ws = (char*)d_ws;
  ushort* wT = (ushort*)ws;                                // 384 KB
  ushort* qb = (ushort*)(ws + 393216);                     // 2 MB
  ushort* kb = (ushort*)(ws + 393216 + 2097152);           // 2 MB
  ushort* vt = (ushort*)(ws + 393216 + 2 * 2097152);       // 2 MB (transposed V)
  // Ppart (25.2 MB, live proj->combine) ALIASES Opart/mlpart (live flash->merge)
  float* Ppart = (float*)(ws + 393216 + 3 * 2097152);      // 25.2 MB
  float* Opart = (float*)(ws + 393216 + 3 * 2097152);      // 16 MB (same region, later)
  float* mlpart = (float*)(ws + 393216 + 3 * 2097152 + 16777216);  // 512 KB

  prep_w<<<dim3(768), dim3(256), 0, stream>>>(wq, wk, wv, wT);
  proj_kernel<<<dim3(256, 3, 2), dim3(256), 0, stream>>>(qsrc, ksrc, vsrc, wT, Ppart);
  combine_kernel<<<dim3(256, 3), dim3(256), 0, stream>>>(Ppart, qb, kb, vt);
  flash_kernel<<<dim3(256), dim3(512), 0, stream>>>(qb, kb, vt, Opart, mlpart);
  merge_kernel<<<dim3(1024), dim3(256), 0, stream>>>(Opart, mlpart, out);
}

// Round 21
// 87.445 us; speedup vs baseline: 1.1151x; 1.1151x over previous
//
#include <hip/hip_runtime.h>
#include <hip/hip_bf16.h>

#define EMBED 1024
#define HEAD 64
#define SEQ 4096

typedef __attribute__((ext_vector_type(8))) short short8;
typedef __attribute__((ext_vector_type(4))) float f32x4;

union S8u { short8 v; uint u[4]; ushort s[8]; };
union U4f { uint4 q; float f[4]; };

// manual RNE f32->bf16 (flash PV path — proven numerics)
__device__ __forceinline__ ushort f2bf(float f) {
  union { float f; uint u; } x; x.f = f;
  return (ushort)((x.u + 0x7fffu + ((x.u >> 16) & 1u)) >> 16);
}

// native cast (proj/prep bulk conversion)
__device__ __forceinline__ ushort f2bf_n(float f) {
  union { __hip_bfloat16 h; ushort u; } cv;
  cv.h = __float2bfloat16(f);
  return cv.u;
}

__device__ __forceinline__ short8 ld16(const ushort* p) {
  uint4 q = *(const uint4*)p;
  S8u t; t.u[0] = q.x; t.u[1] = q.y; t.u[2] = q.z; t.u[3] = q.w;
  return t.v;
}

// ---------------- kernel 1: transpose weights to bf16 wT[t][c][k] ----------------
__global__ __launch_bounds__(256) void prep_w(const float* __restrict__ wq,
                                              const float* __restrict__ wk,
                                              const float* __restrict__ wv,
                                              ushort* __restrict__ wT) {
  int idx = blockIdx.x * 256 + threadIdx.x;
  if (idx >= 3 * HEAD * EMBED) return;
  int t = idx >> 16;
  int rem = idx & 0xFFFF;
  int c = rem >> 10;
  int k = rem & 1023;
  const float* w = (t == 0) ? wq : (t == 1) ? wk : wv;
  wT[idx] = f2bf_n(w[k * HEAD + c]);
}

// ------ kernel 2: projections — round-11-proven LDS-staged pipeline + k-phase stagger
//  per iter: ds_write staged regs -> barrier -> issue next k-chunk's loads (phase-
//  rotated across blocks) -> MFMA from LDS -> barrier ------
__global__ __launch_bounds__(256, 3) void proj_kernel(
    const float* __restrict__ qsrc, const float* __restrict__ ksrc,
    const float* __restrict__ vsrc, const ushort* __restrict__ wT,
    ushort* __restrict__ qb, ushort* __restrict__ kb, ushort* __restrict__ vt) {
  // A f32 [64][64] swizzled @0 (16 KB), B bf16 [64][64] swizzled @16384 (8 KB)
  __shared__ __align__(16) char smem[24576];

  const int t = blockIdx.y;
  const float* src = (t == 0) ? qsrc : (t == 1) ? ksrc : vsrc;
  const ushort* wt = wT + t * (HEAD * EMBED);
  const int tid = threadIdx.x;
  const int lane = tid & 63;
  const int wid = tid >> 6;
  const int c = lane & 15;
  const int g = lane >> 4;
  const int row0 = blockIdx.x * 64;
  const int phase = (blockIdx.x + 5 * blockIdx.y) & 15;   // decorrelate k-chunks (sum reorder)

  // ---- staging addresses (coalesced global, swizzled LDS dest) — r11-proven ----
  const float* gA = src + (size_t)(row0 + (tid >> 4)) * EMBED + (tid & 15) * 4;
  const ushort* gB = wt + (size_t)(tid >> 3) * EMBED + (tid & 7) * 8;
  const int wA = (tid >> 4) * 256 + (((tid & 15) * 16) ^ (((tid >> 4) & 7) << 4));
  const int wB = 16384 + (tid >> 3) * 128 + (((tid & 7) * 16) ^ (((tid >> 3) & 7) << 4));

  // ---- fragment-read offsets ----
  const int rA = (wid * 16 + c) * 256;
  const int swc = (c & 7) << 4;

  f32x4 acc[4];
#pragma unroll
  for (int i = 0; i < 4; ++i) acc[i] = {0.f, 0.f, 0.f, 0.f};

  // prologue: loads for k-chunk 'phase'
  uint4 sA0, sA1, sA2, sA3, sB0, sB1;
  {
    const int ki = phase * 64;
    sA0 = *(const uint4*)(gA + ki);
    sA1 = *(const uint4*)(gA + 16384 + ki);
    sA2 = *(const uint4*)(gA + 32768 + ki);
    sA3 = *(const uint4*)(gA + 49152 + ki);
    sB0 = *(const uint4*)(gB + ki);
    sB1 = *(const uint4*)(gB + 32768 + ki);
  }

  for (int r = 0; r < 16; ++r) {
    // ---- write staged regs to LDS (swizzled dest) ----
    *(uint4*)(smem + wA)         = sA0;
    *(uint4*)(smem + wA + 4096)  = sA1;
    *(uint4*)(smem + wA + 8192)  = sA2;
    *(uint4*)(smem + wA + 12288) = sA3;
    *(uint4*)(smem + wB)         = sB0;
    *(uint4*)(smem + wB + 4096)  = sB1;
    __syncthreads();

    // ---- issue next k-chunk's loads (in flight during compute) ----
    if (r + 1 < 16) {
      const int ki = (((r + 1 + phase) & 15)) * 64;
      sA0 = *(const uint4*)(gA + ki);
      sA1 = *(const uint4*)(gA + 16384 + ki);
      sA2 = *(const uint4*)(gA + 32768 + ki);
      sA3 = *(const uint4*)(gA + 49152 + ki);
      sB0 = *(const uint4*)(gB + ki);
      sB1 = *(const uint4*)(gB + 32768 + ki);
    }

    // ---- compute: 2 k-steps x 4 nf MFMAs from LDS ----
#pragma unroll
    for (int s = 0; s < 2; ++s) {
      U4f af0, af1;
      af0.q = *(const uint4*)(smem + rA + ((128 * s + 32 * g) ^ swc));
      af1.q = *(const uint4*)(smem + rA + ((128 * s + 32 * g + 16) ^ swc));
      S8u a;
      a.s[0] = f2bf_n(af0.f[0]); a.s[1] = f2bf_n(af0.f[1]);
      a.s[2] = f2bf_n(af0.f[2]); a.s[3] = f2bf_n(af0.f[3]);
      a.s[4] = f2bf_n(af1.f[0]); a.s[5] = f2bf_n(af1.f[1]);
      a.s[6] = f2bf_n(af1.f[2]); a.s[7] = f2bf_n(af1.f[3]);
#pragma unroll
      for (int nf = 0; nf < 4; ++nf) {
        uint4 bq = *(const uint4*)(smem + 16384 + (16 * nf + c) * 128 + ((64 * s + 16 * g) ^ swc));
        S8u b; b.u[0] = bq.x; b.u[1] = bq.y; b.u[2] = bq.z; b.u[3] = bq.w;
        acc[nf] = __builtin_amdgcn_mfma_f32_16x16x32_bf16(a.v, b.v, acc[nf], 0, 0, 0);
      }
    }
    __syncthreads();
  }

  // ---- epilogue (proven): q/k row-major, V transposed via LDS (aliases smem) ----
  if (t == 2) {
    ushort (*vtile)[72] = (ushort(*)[72])smem;
#pragma unroll
    for (int nf = 0; nf < 4; ++nf)
#pragma unroll
      for (int rr = 0; rr < 4; ++rr)
        vtile[nf * 16 + c][wid * 16 + 4 * g + rr] = f2bf_n(acc[nf][rr]);
    __syncthreads();
    int d = tid >> 2;
    int s0 = (tid & 3) << 4;
    int bb = row0 >> 12;
    int sbase = row0 & (SEQ - 1);
    ushort* dst = vt + ((size_t)(bb * HEAD + d) << 12) + sbase + s0;
    const uint4* srcp = (const uint4*)&vtile[d][s0];
    *(uint4*)dst = srcp[0];
    *(uint4*)(dst + 8) = srcp[1];
  } else {
    int row_base = row0 + wid * 16 + 4 * g;
    float scale = (t == 0) ? 0.18033688011112042f : 1.0f;  // 0.125*log2(e)
    ushort* dstb = (t == 0) ? qb : kb;
#pragma unroll
    for (int nf = 0; nf < 4; ++nf)
#pragma unroll
      for (int rr = 0; rr < 4; ++rr)
        dstb[(size_t)(row_base + rr) * HEAD + nf * 16 + c] = f2bf_n(acc[nf][rr] * scale);
  }
}

// -- kernel 3: flash attn — 256-q block, 8 waves SHARE each staged KV tile (reuse x8),
//    4-way kv-chunk across blocks, partials to workspace. (round-9-proven, untouched)
__global__ __launch_bounds__(512, 2) void flash_kernel(
    const ushort* __restrict__ qb, const ushort* __restrict__ kb,
    const ushort* __restrict__ vt, float* __restrict__ Opart,
    float* __restrict__ mlpart) {
  __shared__ __align__(16) char smem[16384];   // K tile @0 (8KB), V tile @8192 (8KB)

  const int tid = threadIdx.x;
  const int lane = tid & 63;
  const int w = tid >> 6;
  const int c = lane & 15, g = lane >> 4;

  const int bid = blockIdx.x;
  const int band = 15 - (bid >> 4);
  const int b = (bid >> 2) & 3;
  const int j = bid & 3;
  const int ck = band + 1;
  const int kt0 = j * ck;
  const int q0w = band * 256 + w * 32;

  const int srow = tid >> 3;
  const int scol = (tid & 7) << 4;
  const int sdst = srow * 128 + (scol ^ ((srow & 7) << 4));
  const char* kgp = (const char*)(kb + (size_t)b * SEQ * HEAD) + (size_t)kt0 * 8192 + tid * 16;
  const char* vgp = (const char*)(vt + (size_t)b * HEAD * SEQ) + (size_t)srow * 8192 + kt0 * 128 + scol;

  short8 qa[2][2];
#pragma unroll
  for (int qf = 0; qf < 2; ++qf) {
    const ushort* qrow = qb + (size_t)(b * SEQ + q0w + 16 * qf + c) * HEAD + 8 * g;
    qa[qf][0] = ld16(qrow);
    qa[qf][1] = ld16(qrow + 32);
  }

  f32x4 O[4][2];
#pragma unroll
  for (int i = 0; i < 4; ++i)
#pragma unroll
    for (int qf = 0; qf < 2; ++qf) O[i][qf] = {0.f, 0.f, 0.f, 0.f};
  float m[2] = {-1e30f, -1e30f};
  float l[2] = {0.f, 0.f};

  uint4 sK = *(const uint4*)kgp;
  uint4 sV = *(const uint4*)vgp;

  for (int r = 0; r < ck; ++r) {
    *(uint4*)(smem + sdst) = sK;
    *(uint4*)(smem + 8192 + sdst) = sV;
    __syncthreads();

    if (r + 1 < ck) {
      kgp += 8192; vgp += 128;
      sK = *(const uint4*)kgp;
      sV = *(const uint4*)vgp;
    }

    const int kt = kt0 + r;
    const int k0 = kt << 6;
    if (k0 <= q0w + 31) {
      f32x4 Sf[4][2];
#pragma unroll
      for (int i = 0; i < 4; ++i)
#pragma unroll
        for (int qf = 0; qf < 2; ++qf) Sf[i][qf] = {0.f, 0.f, 0.f, 0.f};
#pragma unroll
      for (int nf = 0; nf < 4; ++nf) {
        int row = 16 * nf + c;
        int sw = (row & 7) << 4;
        uint4 kv = *(const uint4*)(smem + row * 128 + ((16 * g) ^ sw));
        S8u ka0;
        ka0.u[0] = kv.x; ka0.u[1] = kv.y; ka0.u[2] = kv.z; ka0.u[3] = kv.w;
#pragma unroll
        for (int qf = 0; qf < 2; ++qf)
          Sf[nf][qf] = __builtin_amdgcn_mfma_f32_16x16x32_bf16(ka0.v, qa[qf][0], Sf[nf][qf], 0, 0, 0);
        uint4 kv2 = *(const uint4*)(smem + row * 128 + ((64 + 16 * g) ^ sw));
        S8u ka1;
        ka1.u[0] = kv2.x; ka1.u[1] = kv2.y; ka1.u[2] = kv2.z; ka1.u[3] = kv2.w;
#pragma unroll
        for (int qf = 0; qf < 2; ++qf)
          Sf[nf][qf] = __builtin_amdgcn_mfma_f32_16x16x32_bf16(ka1.v, qa[qf][1], Sf[nf][qf], 0, 0, 0);
      }

      if (k0 + 63 > q0w) {
#pragma unroll
        for (int nf = 0; nf < 4; ++nf)
#pragma unroll
          for (int qf = 0; qf < 2; ++qf)
#pragma unroll
            for (int rr = 0; rr < 4; ++rr)
              if (k0 + nf * 16 + 4 * g + rr > q0w + 16 * qf + c) Sf[nf][qf][rr] = -1e30f;
      }

#pragma unroll
      for (int qf = 0; qf < 2; ++qf) {
        float x0 = fmaxf(fmaxf(Sf[0][qf][0], Sf[0][qf][1]), fmaxf(Sf[0][qf][2], Sf[0][qf][3]));
        float x1 = fmaxf(fmaxf(Sf[1][qf][0], Sf[1][qf][1]), fmaxf(Sf[1][qf][2], Sf[1][qf][3]));
        float x2 = fmaxf(fmaxf(Sf[2][qf][0], Sf[2][qf][1]), fmaxf(Sf[2][qf][2], Sf[2][qf][3]));
        float x3 = fmaxf(fmaxf(Sf[3][qf][0], Sf[3][qf][1]), fmaxf(Sf[3][qf][2], Sf[3][qf][3]));
        float rm = fmaxf(fmaxf(x0, x1), fmaxf(x2, x3));
        rm = fmaxf(rm, __shfl_xor(rm, 16));
        rm = fmaxf(rm, __shfl_xor(rm, 32));
        rm = fmaxf(rm, m[qf]);
        float alpha = exp2f(m[qf] - rm);
        m[qf] = rm;
#pragma unroll
        for (int nf = 0; nf < 4; ++nf)
#pragma unroll
          for (int rr = 0; rr < 4; ++rr)
            Sf[nf][qf][rr] = exp2f(Sf[nf][qf][rr] - rm);
        float s0 = (Sf[0][qf][0] + Sf[0][qf][1]) + (Sf[0][qf][2] + Sf[0][qf][3]);
        float s1 = (Sf[1][qf][0] + Sf[1][qf][1]) + (Sf[1][qf][2] + Sf[1][qf][3]);
        float s2 = (Sf[2][qf][0] + Sf[2][qf][1]) + (Sf[2][qf][2] + Sf[2][qf][3]);
        float s3 = (Sf[3][qf][0] + Sf[3][qf][1]) + (Sf[3][qf][2] + Sf[3][qf][3]);
        float rs = (s0 + s1) + (s2 + s3);
        rs += __shfl_xor(rs, 16);
        rs += __shfl_xor(rs, 32);
        l[qf] = l[qf] * alpha + rs;
#pragma unroll
        for (int nf = 0; nf < 4; ++nf)
#pragma unroll
          for (int rr = 0; rr < 4; ++rr)
            O[nf][qf][rr] *= alpha;

#pragma unroll
        for (int sl = 0; sl < 2; ++sl) {
          S8u pa;
#pragma unroll
          for (int rr = 0; rr < 4; ++rr) {
            pa.s[rr]     = f2bf(Sf[2 * sl][qf][rr]);
            pa.s[rr + 4] = f2bf(Sf[2 * sl + 1][qf][rr]);
          }
#pragma unroll
          for (int nf = 0; nf < 4; ++nf) {
            int row = 16 * nf + c;
            int sw = (row & 7) << 4;
            S8u vbf;
            uint2 lo = *(const uint2*)(smem + 8192 + row * 128 + ((64 * sl + 8 * g) ^ sw));
            uint2 hi = *(const uint2*)(smem + 8192 + row * 128 + ((64 * sl + 32 + 8 * g) ^ sw));
            vbf.u[0] = lo.x; vbf.u[1] = lo.y; vbf.u[2] = hi.x; vbf.u[3] = hi.y;
            O[nf][qf] = __builtin_amdgcn_mfma_f32_16x16x32_bf16(vbf.v, pa.v, O[nf][qf], 0, 0, 0);
          }
        }
      }
    }
    __syncthreads();
  }

  const size_t pi = (size_t)((b * 16 + band) * 4 + j);
#pragma unroll
  for (int qf = 0; qf < 2; ++qf) {
    int ql = w * 32 + 16 * qf + c;
#pragma unroll
    for (int nf = 0; nf < 4; ++nf)
      *(f32x4*)&Opart[pi * 16384 + (size_t)ql * 64 + 16 * nf + 4 * g] = O[nf][qf];
    if (g == 0) {
      mlpart[pi * 512 + ql * 2]     = m[qf];
      mlpart[pi * 512 + ql * 2 + 1] = l[qf];
    }
  }
}

// ---------------- kernel 4: merge the 4 kv-chunk partials per band ----------------
__global__ __launch_bounds__(256) void merge_kernel(const float* __restrict__ Opart,
                                                    const float* __restrict__ mlpart,
                                                    float* __restrict__ out) {
  int i = blockIdx.x * 256 + threadIdx.x;
  int dq = i & 15;
  int row = i >> 4;
  int b = row >> 12;
  int qrow = row & 4095;
  int band = qrow >> 8;
  int q = qrow & 255;
  size_t pi0 = (size_t)((b * 16 + band) * 4);

  float mm[4], M = -1e30f;
#pragma unroll
  for (int jj = 0; jj < 4; ++jj) { mm[jj] = mlpart[(pi0 + jj) * 512 + q * 2]; M = fmaxf(M, mm[jj]); }
  float wgt[4], L = 0.f;
#pragma unroll
  for (int jj = 0; jj < 4; ++jj) {
    wgt[jj] = exp2f(mm[jj] - M);
    L += wgt[jj] * mlpart[(pi0 + jj) * 512 + q * 2 + 1];
  }
  f32x4 acc = {0.f, 0.f, 0.f, 0.f};
#pragma unroll
  for (int jj = 0; jj < 4; ++jj) {
    f32x4 t = *(const f32x4*)&Opart[(pi0 + jj) * 16384 + (size_t)q * 64 + 4 * dq];
#pragma unroll
    for (int rr = 0; rr < 4; ++rr) acc[rr] += wgt[jj] * t[rr];
  }
  float inv = 1.0f / L;
  f32x4 res;
#pragma unroll
  for (int rr = 0; rr < 4; ++rr) res[rr] = acc[rr] * inv;
  *(f32x4*)&out[(size_t)row * HEAD + 4 * dq] = res;
}

extern "C" void kernel_launch(void* const* d_in, const int* in_sizes, int n_in,
                              void* d_out, int out_size, void* d_ws, size_t ws_size,
                              hipStream_t stream) {
  const float* qsrc = (const float*)d_in[0];
  const float* ksrc = (const float*)d_in[1];
  const float* vsrc = (const float*)d_in[2];
  const float* wq = (const float*)d_in[3];
  const float* wk = (const float*)d_in[4];
  const float* wv = (const float*)d_in[5];
  float* out = (float*)d_out;

  char* ws = (char*)d_ws;
  ushort* wT = (ushort*)ws;                                // 384 KB
  ushort* qb = (ushort*)(ws + 393216);                     // 2 MB
  ushort* kb = (ushort*)(ws + 393216 + 2097152);           // 2 MB
  ushort* vt = (ushort*)(ws + 393216 + 2 * 2097152);       // 2 MB (transposed V)
  float* Opart = (float*)(ws + 393216 + 3 * 2097152);      // 16 MB
  float* mlpart = (float*)(ws + 393216 + 3 * 2097152 + 16777216);  // 512 KB

  prep_w<<<dim3(768), dim3(256), 0, stream>>>(wq, wk, wv, wT);
  proj_kernel<<<dim3(256, 3), dim3(256), 0, stream>>>(qsrc, ksrc, vsrc, wT, qb, kb, vt);
  flash_kernel<<<dim3(256), dim3(512), 0, stream>>>(qb, kb, vt, Opart, mlpart);
  merge_kernel<<<dim3(1024), dim3(256), 0, stream>>>(Opart, mlpart, out);
}